// Round 3
// baseline (136.041 us; speedup 1.0000x reference)
//
#include <hip/hip_runtime.h>
#include <hip/hip_bf16.h>

typedef _Float16 half2v __attribute__((ext_vector_type(2)));
typedef _Float16 half8 __attribute__((ext_vector_type(8)));
typedef __attribute__((ext_vector_type(4))) float floatx4;
typedef __attribute__((ext_vector_type(4))) unsigned int uintx4;

#define GLOBAL_AS __attribute__((address_space(1)))
#define LDS_AS __attribute__((address_space(3)))

// async 16B/lane global->LDS DMA. LDS dest = WAVE-uniform base + lane*16.
__device__ __forceinline__ void async_ld16(const void* g, void* l) {
  __builtin_amdgcn_global_load_lds((const GLOBAL_AS unsigned int*)g,
                                   (LDS_AS unsigned int*)l, 16, 0, 0);
}

__device__ __forceinline__ half2v h2(float v) {
  return (half2v){(_Float16)v, (_Float16)v};
}

// tanh(x0),tanh(x1) -> packed-f16 Legendre P1..P8 for BOTH elements.
// fa0 = low halves (elem0), fa1 = high halves (elem1). ~42 VALU total.
__device__ __forceinline__ void legendre2_f16(float xv0, float xv1,
                                              half8* fa0, half8* fa1) {
  float e0 = __builtin_amdgcn_exp2f(xv0 * 2.885390081777927f); // 2*log2(e)
  float t0 = 1.0f - 2.0f * __builtin_amdgcn_rcpf(e0 + 1.0f);
  float e1 = __builtin_amdgcn_exp2f(xv1 * 2.885390081777927f);
  float t1 = 1.0f - 2.0f * __builtin_amdgcn_rcpf(e1 + 1.0f);
  half2v t;
  { auto tt = __builtin_amdgcn_cvt_pkrtz(t0, t1); __builtin_memcpy(&t, &tt, 4); }
  // P_k = u + c_k*(u - P_{k-2}), u = t*P_{k-1}, c_k=(k-1)/k   (packed, 3 ops/deg)
  half2v p1 = t;
  half2v u2 = t * p1, w2 = u2 - h2(1.0f);  half2v p2 = h2(0.5f)      * w2 + u2;
  half2v u3 = t * p2, w3 = u3 - p1;        half2v p3 = h2(2.0f/3.0f) * w3 + u3;
  half2v u4 = t * p3, w4 = u4 - p2;        half2v p4 = h2(0.75f)     * w4 + u4;
  half2v u5 = t * p4, w5 = u5 - p3;        half2v p5 = h2(0.8f)      * w5 + u5;
  half2v u6 = t * p5, w6 = u6 - p4;        half2v p6 = h2(5.0f/6.0f) * w6 + u6;
  half2v u7 = t * p6, w7 = u7 - p5;        half2v p7 = h2(6.0f/7.0f) * w7 + u7;
  half2v u8 = t * p7, w8 = u8 - p6;        half2v p8 = h2(7.0f/8.0f) * w8 + u8;
  unsigned P[8];
  __builtin_memcpy(&P[0], &p1, 4); __builtin_memcpy(&P[1], &p2, 4);
  __builtin_memcpy(&P[2], &p3, 4); __builtin_memcpy(&P[3], &p4, 4);
  __builtin_memcpy(&P[4], &p5, 4); __builtin_memcpy(&P[5], &p6, 4);
  __builtin_memcpy(&P[6], &p7, 4); __builtin_memcpy(&P[7], &p8, 4);
  union { unsigned u[4]; half8 h; } a0, a1;
#pragma unroll
  for (int j = 0; j < 4; ++j) {
    a0.u[j] = __builtin_amdgcn_perm(P[2*j+1], P[2*j], 0x05040100u); // low halves
    a1.u[j] = __builtin_amdgcn_perm(P[2*j+1], P[2*j], 0x07060302u); // high halves
  }
  *fa0 = a0.h;
  *fa1 = a1.h;
}

// ---- kernel 1: c_basis fp32 -> f16, transposed to ws[i][o][d] (256 KB) ----
__global__ void conv_kernel(const float* __restrict__ cb, _Float16* __restrict__ ws) {
  int t = blockIdx.x * 128 + threadIdx.x;   // 0..16383 = (o,i)
  int o = t >> 8;
  int i = t & 255;
  const floatx4* s = (const floatx4*)(cb + ((size_t)o * 256 + i) * 8);
  floatx4 v0 = s[0], v1 = s[1];
  union { _Float16 h[8]; uintx4 u; } w;
  w.h[0] = (_Float16)v0.x; w.h[1] = (_Float16)v0.y;
  w.h[2] = (_Float16)v0.z; w.h[3] = (_Float16)v0.w;
  w.h[4] = (_Float16)v1.x; w.h[5] = (_Float16)v1.y;
  w.h[6] = (_Float16)v1.z; w.h[7] = (_Float16)v1.w;
  *(uintx4*)(ws + (size_t)i * 512 + o * 8) = w.u;
}

// ---- kernel 2: barrier-free K-split ----
// 128 thr (2 waves), 32 rows/block, grid 2048 -> 8 blocks/CU (LDS 16 KB)
// = 16 waves/CU = 4 waves/SIMD. Wave w owns K-half i in [w*128, w*128+128),
// i-map: i = w*128 + q*32 + ch  (q = lane>>4, ch = chunk 0..31).
// Each wave double-buffers its PRIVATE 4 KB B-chunk (4 i-rows x 1 KB) via
// global_load_lds -> no inter-wave barriers in the main loop.
// Gate discipline (R2 bug fix): per chunk, program+sched_barrier-pinned order
// is [x-prefetch] -> [stage(ch+1) 4 DMA] -> legendre -> vmcnt gate. The gate
// uses N = 4 + 2*DOX(ch): ops guaranteed issued after stage(ch) in ANY legal
// schedule (x(ch) + stage(ch+1)), so stage(ch) is always drained; never waits
// on the just-issued prefetches (depth-1 pipeline preserved).
// x: rolling 3-deep float4 window per lane (group g = cols q*32+4g..+3),
// prefetched 2 groups (8 chunks) ahead. Epilogue: LDS reduce of K-partials.
__global__ __launch_bounds__(128, 4) void kan_kernel(
    const float* __restrict__ x, const _Float16* __restrict__ ws,
    const float* __restrict__ bias, float* __restrict__ y) {
  // [wave][buf][t*512 + o*8 + d] halves; 2*2*2048*2B = 16 KB
  __shared__ __align__(16) _Float16 bt[2][2][2048];

  const int tid  = threadIdx.x;
  const int wid  = tid >> 6;    // 0..1 = K-half
  const int lane = tid & 63;
  const int m    = lane & 15;
  const int q    = lane >> 4;
  const int rb   = blockIdx.x * 32;

  floatx4 acc[2][4];
#pragma unroll
  for (int a = 0; a < 2; ++a)
#pragma unroll
    for (int nt = 0; nt < 4; ++nt) acc[a][nt] = (floatx4){0.f, 0.f, 0.f, 0.f};

  // B staging src pointers: DMA t loads i-row i = wid*128 + t*32 + ch (1 KB)
  const _Float16* bs0 = ws + (size_t)(wid * 128 +  0) * 512 + lane * 8;
  const _Float16* bs1 = ws + (size_t)(wid * 128 + 32) * 512 + lane * 8;
  const _Float16* bs2 = ws + (size_t)(wid * 128 + 64) * 512 + lane * 8;
  const _Float16* bs3 = ws + (size_t)(wid * 128 + 96) * 512 + lane * 8;

  // x: rows rb+m (stream 0) and rb+16+m (stream 1); cols wid*128 + q*32 + ...
  const float* xp0 = x + (size_t)(rb + m) * 256 + wid * 128 + q * 32;
  const float* xp1 = xp0 + 16 * 256;

  // rolling 3-deep x window: slot g%3 holds group g (4 cols)
  floatx4 xs0[3], xs1[3];
  xs0[0] = *(const floatx4*)(xp0);     xs1[0] = *(const floatx4*)(xp1);
  xs0[1] = *(const floatx4*)(xp0 + 4); xs1[1] = *(const floatx4*)(xp1 + 4);
  __builtin_amdgcn_sched_barrier(0);

  // prologue: stage chunk 0 into buf 0
  {
    _Float16* ld = &bt[wid][0][0];
    async_ld16(bs0, ld);        async_ld16(bs1, ld + 512);
    async_ld16(bs2, ld + 1024); async_ld16(bs3, ld + 1536);
    bs0 += 512; bs1 += 512; bs2 += 512; bs3 += 512;
  }
  __builtin_amdgcn_sched_barrier(0);

#define CHUNK(ch, N, DOX)                                                      \
  {                                                                            \
    if constexpr (DOX) {                                                       \
      constexpr int gp = (ch) / 4 + 2;                                         \
      xs0[gp % 3] = *(const floatx4*)(xp0 + gp * 4);                           \
      xs1[gp % 3] = *(const floatx4*)(xp1 + gp * 4);                           \
    }                                                                          \
    __builtin_amdgcn_sched_barrier(0);                                         \
    if constexpr ((ch) < 31) {                                                 \
      _Float16* ld = &bt[wid][((ch) + 1) & 1][0];                              \
      async_ld16(bs0, ld);        async_ld16(bs1, ld + 512);                   \
      async_ld16(bs2, ld + 1024); async_ld16(bs3, ld + 1536);                  \
      bs0 += 512; bs1 += 512; bs2 += 512; bs3 += 512;                          \
    }                                                                          \
    __builtin_amdgcn_sched_barrier(0);                                         \
    half8 f0, f1;                                                              \
    legendre2_f16(xs0[((ch) / 4) % 3][(ch) % 4],                               \
                  xs1[((ch) / 4) % 3][(ch) % 4], &f0, &f1);                    \
    asm volatile("s_waitcnt vmcnt(" #N ")" ::: "memory");                      \
    const _Float16* bp = &bt[wid][(ch) & 1][q * 512 + m * 8];                  \
    half8 fb0 = *(const half8*)(bp + 0);                                       \
    half8 fb1 = *(const half8*)(bp + 128);                                     \
    half8 fb2 = *(const half8*)(bp + 256);                                     \
    half8 fb3 = *(const half8*)(bp + 384);                                     \
    __builtin_amdgcn_s_setprio(1);                                             \
    acc[0][0] = __builtin_amdgcn_mfma_f32_16x16x32_f16(f0, fb0, acc[0][0], 0, 0, 0); \
    acc[1][0] = __builtin_amdgcn_mfma_f32_16x16x32_f16(f1, fb0, acc[1][0], 0, 0, 0); \
    acc[0][1] = __builtin_amdgcn_mfma_f32_16x16x32_f16(f0, fb1, acc[0][1], 0, 0, 0); \
    acc[1][1] = __builtin_amdgcn_mfma_f32_16x16x32_f16(f1, fb1, acc[1][1], 0, 0, 0); \
    acc[0][2] = __builtin_amdgcn_mfma_f32_16x16x32_f16(f0, fb2, acc[0][2], 0, 0, 0); \
    acc[1][2] = __builtin_amdgcn_mfma_f32_16x16x32_f16(f1, fb2, acc[1][2], 0, 0, 0); \
    acc[0][3] = __builtin_amdgcn_mfma_f32_16x16x32_f16(f0, fb3, acc[0][3], 0, 0, 0); \
    acc[1][3] = __builtin_amdgcn_mfma_f32_16x16x32_f16(f1, fb3, acc[1][3], 0, 0, 0); \
    __builtin_amdgcn_s_setprio(0);                                             \
  }

  CHUNK(0, 6, 1)  CHUNK(1, 4, 0)  CHUNK(2, 4, 0)  CHUNK(3, 4, 0)
  CHUNK(4, 6, 1)  CHUNK(5, 4, 0)  CHUNK(6, 4, 0)  CHUNK(7, 4, 0)
  CHUNK(8, 6, 1)  CHUNK(9, 4, 0)  CHUNK(10, 4, 0) CHUNK(11, 4, 0)
  CHUNK(12, 6, 1) CHUNK(13, 4, 0) CHUNK(14, 4, 0) CHUNK(15, 4, 0)
  CHUNK(16, 6, 1) CHUNK(17, 4, 0) CHUNK(18, 4, 0) CHUNK(19, 4, 0)
  CHUNK(20, 6, 1) CHUNK(21, 4, 0) CHUNK(22, 4, 0) CHUNK(23, 4, 0)
  CHUNK(24, 4, 0) CHUNK(25, 4, 0) CHUNK(26, 4, 0) CHUNK(27, 4, 0)
  CHUNK(28, 4, 0) CHUNK(29, 4, 0) CHUNK(30, 4, 0) CHUNK(31, 0, 0)
#undef CHUNK

  // ---- epilogue: reduce the two K-partials through LDS, add bias, store ----
  float* red = (float*)&bt[0][0][0];   // 8 KB scratch, reuse staging LDS
  __syncthreads();                     // both waves done with all LDS/DMA
  if (wid) {
#pragma unroll
    for (int a = 0; a < 2; ++a)
#pragma unroll
      for (int nt = 0; nt < 4; ++nt)
        *(floatx4*)(red + ((a * 4 + nt) * 64 + lane) * 4) = acc[a][nt];
  }
  __syncthreads();
  if (!wid) {
    float bv[4];
#pragma unroll
    for (int nt = 0; nt < 4; ++nt) bv[nt] = bias[nt * 16 + m];
#pragma unroll
    for (int a = 0; a < 2; ++a) {
      int gr0 = rb + a * 16 + q * 4;
#pragma unroll
      for (int nt = 0; nt < 4; ++nt) {
        floatx4 p = *(const floatx4*)(red + ((a * 4 + nt) * 64 + lane) * 4);
#pragma unroll
        for (int r = 0; r < 4; ++r) {
          y[(size_t)(gr0 + r) * 64 + nt * 16 + m] = acc[a][nt][r] + p[r] + bv[nt];
        }
      }
    }
  }
}

extern "C" void kernel_launch(void* const* d_in, const int* in_sizes, int n_in,
                              void* d_out, int out_size, void* d_ws, size_t ws_size,
                              hipStream_t stream) {
  const float* x    = (const float*)d_in[0];
  const float* cb   = (const float*)d_in[1];
  const float* bias = (const float*)d_in[2];
  float* y = (float*)d_out;
  _Float16* ws = (_Float16*)d_ws;
  int batch = in_sizes[0] / 256;  // 65536
  hipLaunchKernelGGL(conv_kernel, dim3(128), dim3(128), 0, stream, cb, ws);
  hipLaunchKernelGGL(kan_kernel, dim3(batch / 32), dim3(128), 0, stream, x, ws, bias, y);
}